// Round 1
// baseline (668.212 us; speedup 1.0000x reference)
//
#include <hip/hip_runtime.h>
#include <math.h>

// ---------------------------------------------------------------------------
// GCNRecommender: 3x GCNConv (D=64) + linear head. N=300K nodes, E=1.2M edges.
// R5: k_gemm was LDS-BW-bound (128 ds_read_b128/thread = 2 B/FLOP; VALUBusy
// 30% ~= 2048/6160 cyc). New GEMM: no Xs tile -- X read directly from global
// (16-lane broadcast per row, L1-served), only W (16 KB) in LDS -> 1 B/FLOP
// LDS, 2x residency, one barrier. ReLU moved from GEMM load (64x/elem) to
// gather epilogue (1x/elem). All fp32.
// ---------------------------------------------------------------------------

// ---- CSR build -------------------------------------------------------------

__global__ void k_hist(const int* __restrict__ col, int* __restrict__ cnt, int e) {
    int i = blockIdx.x * blockDim.x + threadIdx.x;
    if (i < e) atomicAdd(&cnt[col[i]], 1);
}

// exclusive scan, 1024 elems/block (256 thr x 4)
__global__ void k_scan1(const int* __restrict__ cnt, int* __restrict__ offs,
                        int* __restrict__ bsum, int n) {
    __shared__ int s[256];
    const int t = threadIdx.x;
    const int base = blockIdx.x * 1024 + t * 4;
    int v[4], sum = 0;
    #pragma unroll
    for (int k = 0; k < 4; ++k) {
        v[k] = (base + k < n) ? cnt[base + k] : 0;
        sum += v[k];
    }
    s[t] = sum;
    __syncthreads();
    #pragma unroll
    for (int off = 1; off < 256; off <<= 1) {
        int x = (t >= off) ? s[t - off] : 0;
        __syncthreads();
        s[t] += x;
        __syncthreads();
    }
    int run = s[t] - sum;
    #pragma unroll
    for (int k = 0; k < 4; ++k) {
        if (base + k < n) offs[base + k] = run;
        run += v[k];
    }
    if (t == 255) bsum[blockIdx.x] = s[255];
}

__global__ void k_scan2(int* __restrict__ bsum, int nb) {
    __shared__ int s[512];
    const int t = threadIdx.x;
    int v = (t < nb) ? bsum[t] : 0;
    s[t] = v;
    __syncthreads();
    #pragma unroll
    for (int off = 1; off < 512; off <<= 1) {
        int x = (t >= off) ? s[t - off] : 0;
        __syncthreads();
        s[t] += x;
        __syncthreads();
    }
    if (t < nb) bsum[t] = s[t] - v;
}

__global__ void k_scan3(int* __restrict__ offs, const int* __restrict__ bsum,
                        int n, int e) {
    int i = blockIdx.x * blockDim.x + threadIdx.x;
    if (i < n) offs[i] += bsum[i >> 10];
    if (i == 0) offs[n] = e;
}

__global__ void k_fill(const int* __restrict__ row, const int* __restrict__ col,
                       const int* __restrict__ offs, int* __restrict__ cur,
                       int* __restrict__ elist, int e) {
    int i = blockIdx.x * blockDim.x + threadIdx.x;
    if (i < e) {
        int c = col[i];
        int pos = offs[c] + atomicAdd(&cur[c], 1);
        elist[pos] = row[i];
    }
}

__global__ void k_dinv(const int* __restrict__ cnt, float* __restrict__ dinv, int n) {
    int i = blockIdx.x * blockDim.x + threadIdx.x;
    if (i < n) dinv[i] = 1.0f / sqrtf((float)(cnt[i] + 1));  // +1 self-loop
}

// ---- GEMM: Y[r,:] = X[r,:] @ W ---------------------------------------------
// X source: (ut!=null) ? embedding tables (conv1) : dense X.
// No X LDS tile: thread (cg=t&15, rbase=t>>4) handles rows rbase+16j; the 16
// cg-lanes of a row issue the SAME global address (HW broadcast, L1-hit after
// first touch; each 128B line consumed 8x by one wave). Only W in LDS (16 KB)
// -> LDS traffic 1 B/FLOP (was 2), residency up to 8 blocks/CU (was 4).
// Epilogue: dinv!=null -> Y = dinv[row]*y (conv; bias+relu in gather)
//           dinv==null -> Y = y + bias   (linear head)
__launch_bounds__(256, 4)
__global__ void k_gemm(const float* __restrict__ X,
                       const int* __restrict__ uid, const int* __restrict__ iid,
                       const float4* __restrict__ ut4, const float4* __restrict__ it4,
                       const float* __restrict__ W, const float* __restrict__ bias,
                       float* __restrict__ Y, const float* __restrict__ dinv,
                       int n, int u) {
    __shared__ __align__(16) float Ws[64 * 64];
    const int t  = threadIdx.x;
    const int rb = blockIdx.x * 64;

    const float4* W4 = (const float4*)W;
    float4* Ws4 = (float4*)Ws;
    #pragma unroll
    for (int idx = t; idx < 1024; idx += 256) Ws4[idx] = W4[idx];

    const int cg = t & 15;     // float4 col group
    const int rbase = t >> 4;  // rows rbase+16j

    // Per-j source pointers (row clamped for the ragged last block; store is
    // guarded so clamped rows produce no output).
    const float4* X4 = (const float4*)X;
    const float4* src[4];
    int rows[4];
    #pragma unroll
    for (int j = 0; j < 4; ++j) {
        int row_g = rb + rbase + 16 * j;
        rows[j] = row_g;
        int rc = min(row_g, n - 1);
        if (ut4 != nullptr) {
            src[j] = (rc < u) ? (ut4 + (size_t)uid[rc] * 16)
                              : (it4 + (size_t)iid[rc - u] * 16);
        } else {
            src[j] = X4 + (size_t)rc * 16;
        }
    }
    __syncthreads();

    float4 acc[4];
    #pragma unroll
    for (int j = 0; j < 4; ++j) acc[j] = make_float4(0.f, 0.f, 0.f, 0.f);

    #pragma unroll 2
    for (int kg = 0; kg < 16; ++kg) {
        float4 w0 = Ws4[(4 * kg + 0) * 16 + cg];
        float4 w1 = Ws4[(4 * kg + 1) * 16 + cg];
        float4 w2 = Ws4[(4 * kg + 2) * 16 + cg];
        float4 w3 = Ws4[(4 * kg + 3) * 16 + cg];
        #pragma unroll
        for (int j = 0; j < 4; ++j) {
            float4 xr = src[j][kg];  // broadcast across the 16 cg-lanes
            acc[j].x = fmaf(xr.x, w0.x, acc[j].x); acc[j].y = fmaf(xr.x, w0.y, acc[j].y);
            acc[j].z = fmaf(xr.x, w0.z, acc[j].z); acc[j].w = fmaf(xr.x, w0.w, acc[j].w);
            acc[j].x = fmaf(xr.y, w1.x, acc[j].x); acc[j].y = fmaf(xr.y, w1.y, acc[j].y);
            acc[j].z = fmaf(xr.y, w1.z, acc[j].z); acc[j].w = fmaf(xr.y, w1.w, acc[j].w);
            acc[j].x = fmaf(xr.z, w2.x, acc[j].x); acc[j].y = fmaf(xr.z, w2.y, acc[j].y);
            acc[j].z = fmaf(xr.z, w2.z, acc[j].z); acc[j].w = fmaf(xr.z, w2.w, acc[j].w);
            acc[j].x = fmaf(xr.w, w3.x, acc[j].x); acc[j].y = fmaf(xr.w, w3.y, acc[j].y);
            acc[j].z = fmaf(xr.w, w3.z, acc[j].z); acc[j].w = fmaf(xr.w, w3.w, acc[j].w);
        }
    }

    const float4* b4 = (const float4*)bias;
    #pragma unroll
    for (int j = 0; j < 4; ++j) {
        int row = rows[j];
        if (row >= n) continue;
        float4 y = acc[j];
        if (dinv != nullptr) {
            float s = dinv[row];
            y.x *= s; y.y *= s; y.z *= s; y.w *= s;
        } else {
            float4 bb = b4[cg];
            y.x += bb.x; y.y += bb.y; y.z += bb.z; y.w += bb.w;
        }
        ((float4*)Y)[(size_t)row * 16 + cg] = y;
    }
}

// ---- gather: 16 lanes per node (4 nodes/wave, 16 nodes/block).
// OUT[c,:] = f( dinv[c] * (sum_{r in in(c)} Yn[r,:] + Yn[c,:]) + b ),
// f = relu (conv1/conv2 outputs) or identity (conv3 output).
__launch_bounds__(256)
__global__ void k_gather(const int* __restrict__ offs, const int* __restrict__ elist,
                         const float* __restrict__ dinv, const float4* __restrict__ Yn4,
                         const float4* __restrict__ b4, float4* __restrict__ OUT4,
                         int n, int relu_out) {
    const int t = threadIdx.x;
    const int nid = blockIdx.x * 16 + (t >> 4);  // this 16-lane group's node
    const int q = t & 15;                        // float4 column group
    const int gbase = t & 48;                    // first lane of this group
    if (nid >= n) return;

    const int beg = offs[nid];
    const int end = offs[nid + 1];
    const int deg = end - beg;

    // Issue independent loads early: self row, dinv, bias, first 16 edge idx.
    float4 self = Yn4[(size_t)nid * 16 + q];
    float dc = dinv[nid];
    float4 bb = b4[q];
    int eidx = (q < deg) ? elist[beg + q] : 0;

    // wave-wide max degree (groups diverge only in predicates, not trip count)
    int m = deg;
    m = max(m, __shfl_xor(m, 16, 64));
    m = max(m, __shfl_xor(m, 32, 64));
    m = min(m, 16);

    float4 acc = make_float4(0.f, 0.f, 0.f, 0.f);
    for (int j = 0; j < m; ++j) {
        int r = __shfl(eidx, gbase + j, 64);  // broadcast j-th edge of my group
        if (j < deg) {
            float4 v = Yn4[(size_t)r * 16 + q];
            acc.x += v.x; acc.y += v.y; acc.z += v.z; acc.w += v.w;
        }
    }
    // rare tail (deg > 16): ~0 nodes for Poisson(4), correctness only
    for (int jj = beg + 16; jj < end; ++jj) {
        int r = elist[jj];
        float4 v = Yn4[(size_t)r * 16 + q];
        acc.x += v.x; acc.y += v.y; acc.z += v.z; acc.w += v.w;
    }

    float4 o;
    o.x = fmaf(dc, acc.x + self.x, bb.x);
    o.y = fmaf(dc, acc.y + self.y, bb.y);
    o.z = fmaf(dc, acc.z + self.z, bb.z);
    o.w = fmaf(dc, acc.w + self.w, bb.w);
    if (relu_out) {
        o.x = fmaxf(o.x, 0.f); o.y = fmaxf(o.y, 0.f);
        o.z = fmaxf(o.z, 0.f); o.w = fmaxf(o.w, 0.f);
    }
    OUT4[(size_t)nid * 16 + q] = o;
}

// ---------------------------------------------------------------------------

extern "C" void kernel_launch(void* const* d_in, const int* in_sizes, int n_in,
                              void* d_out, int out_size, void* d_ws, size_t ws_size,
                              hipStream_t stream) {
    const int*   user_ids = (const int*)d_in[0];
    const int*   item_ids = (const int*)d_in[1];
    const int*   edge     = (const int*)d_in[2];
    const float* ut   = (const float*)d_in[4];
    const float* it   = (const float*)d_in[5];
    const float* W1   = (const float*)d_in[6];
    const float* b1   = (const float*)d_in[7];
    const float* W2   = (const float*)d_in[8];
    const float* b2   = (const float*)d_in[9];
    const float* W3   = (const float*)d_in[10];
    const float* b3   = (const float*)d_in[11];
    const float* linW = (const float*)d_in[12];
    const float* linb = (const float*)d_in[13];

    const int u = in_sizes[0];
    const int iN = in_sizes[1];
    const int e = in_sizes[2] / 2;
    const int n = u + iN;

    // workspace layout
    float* A    = (float*)d_ws;                       // [n,64] node features
    float* dinv = A + (size_t)n * 64;                 // [n]
    int*   cnt  = (int*)(dinv + n);                   // [n]  (reused as cursor)
    int*   offs = cnt + n;                            // [n+1]
    int*   bsum = offs + n + 1;                       // [nb]
    int*   elist = bsum + 1024;                       // [e]
    float* Yn   = (float*)d_out;                      // [n,64] scratch; final out

    const int* erow = edge;
    const int* ecol = edge + e;

    const int B = 256;
    const int nb = (n + 1023) / 1024;

    // ---- CSR build + dinv ----
    hipMemsetAsync(cnt, 0, (size_t)n * sizeof(int), stream);
    k_hist<<<(e + B - 1) / B, B, 0, stream>>>(ecol, cnt, e);
    k_scan1<<<nb, 256, 0, stream>>>(cnt, offs, bsum, n);
    k_scan2<<<1, 512, 0, stream>>>(bsum, nb);
    k_scan3<<<(n + B - 1) / B, B, 0, stream>>>(offs, bsum, n, e);
    k_dinv<<<(n + B - 1) / B, B, 0, stream>>>(cnt, dinv, n);
    hipMemsetAsync(cnt, 0, (size_t)n * sizeof(int), stream);  // cursor
    k_fill<<<(e + B - 1) / B, B, 0, stream>>>(erow, ecol, offs, cnt, elist, e);

    const int gemm_grid = (n + 63) / 64;
    const int gath_grid = (n + 15) / 16;  // 16 nodes/block (16 lanes/node)

    // conv1 (embed fused into GEMM address calc)
    k_gemm<<<gemm_grid, B, 0, stream>>>(nullptr, user_ids, item_ids,
                                        (const float4*)ut, (const float4*)it,
                                        W1, nullptr, Yn, dinv, n, u);
    k_gather<<<gath_grid, B, 0, stream>>>(offs, elist, dinv, (const float4*)Yn,
                                          (const float4*)b1, (float4*)A, n, 1);
    // conv2 (relu already applied at gather1 store)
    k_gemm<<<gemm_grid, B, 0, stream>>>(A, nullptr, nullptr, nullptr, nullptr,
                                        W2, nullptr, Yn, dinv, n, u);
    k_gather<<<gath_grid, B, 0, stream>>>(offs, elist, dinv, (const float4*)Yn,
                                          (const float4*)b2, (float4*)A, n, 1);
    // conv3
    k_gemm<<<gemm_grid, B, 0, stream>>>(A, nullptr, nullptr, nullptr, nullptr,
                                        W3, nullptr, Yn, dinv, n, u);
    k_gather<<<gath_grid, B, 0, stream>>>(offs, elist, dinv, (const float4*)Yn,
                                          (const float4*)b3, (float4*)A, n, 0);
    // mean-pool = identity; linear head -> d_out
    k_gemm<<<gemm_grid, B, 0, stream>>>(A, nullptr, nullptr, nullptr, nullptr,
                                        linW, linb, (float*)d_out, nullptr, n, u);
}